// Round 12
// baseline (460.691 us; speedup 1.0000x reference)
//
#include <hip/hip_runtime.h>
#include <hip/hip_bf16.h>
#include <stdint.h>

#define D_DIM 1024
#define P_ROWS 8192
#define K_ROWS 131072
#define M_DIM 512
#define L_STEPS 64
#define BM 128
#define XS_ROW_BYTES 4096

typedef short bf16x8_t __attribute__((ext_vector_type(8)));
typedef float f32x4_t __attribute__((ext_vector_type(4)));

__device__ __forceinline__ uint32_t f2bf(float f) {
  union { float f; uint32_t u; } c; c.f = f;
  const uint32_t u = c.u;
  return (u + 0x7FFFu + ((u >> 16) & 1u)) >> 16;   // RNE
}

__device__ __forceinline__ bf16x8_t as_bf16x8(uint4 v) {
  union { uint4 u; bf16x8_t h; } c; c.u = v; return c.h;
}

__device__ __forceinline__ bf16x8_t cvt_frag(const f32x4_t& a0, const f32x4_t& a1) {
  uint32_t p0, p1, p2, p3;
  asm("v_cvt_pk_bf16_f32 %0, %1, %2" : "=v"(p0) : "v"(a0[0]), "v"(a0[1]));
  asm("v_cvt_pk_bf16_f32 %0, %1, %2" : "=v"(p1) : "v"(a0[2]), "v"(a0[3]));
  asm("v_cvt_pk_bf16_f32 %0, %1, %2" : "=v"(p2) : "v"(a1[0]), "v"(a1[1]));
  asm("v_cvt_pk_bf16_f32 %0, %1, %2" : "=v"(p3) : "v"(a1[2]), "v"(a1[3]));
  union { uint32_t u[4]; bf16x8_t h; } c;
  c.u[0] = p0; c.u[1] = p1; c.u[2] = p2; c.u[3] = p3;
  return c.h;
}

// v[d] += sum_i y[i] * X[i,d]
__global__ void xty_kernel(const float* __restrict__ X, const float* __restrict__ y,
                           float* __restrict__ v) {
  const int d0 = threadIdx.x * 4;
  float a0 = 0.f, a1 = 0.f, a2 = 0.f, a3 = 0.f;
  for (int i = blockIdx.x; i < P_ROWS; i += gridDim.x) {
    const float s = y[i];
    const float4 x = *reinterpret_cast<const float4*>(X + (size_t)i * D_DIM + d0);
    a0 += s * x.x; a1 += s * x.y; a2 += s * x.z; a3 += s * x.w;
  }
  atomicAdd(v + d0 + 0, a0);
  atomicAdd(v + d0 + 1, a1);
  atomicAdd(v + d0 + 2, a2);
  atomicAdd(v + d0 + 3, a3);
}

// wout[d] += sum_i (X[i,:].win) * X[i,d]
__global__ void xtxw_kernel(const float* __restrict__ X, const float* __restrict__ win,
                            float* __restrict__ wout) {
  __shared__ float red[4][D_DIM];
  const int lane = threadIdx.x & 63;
  const int wave = threadIdx.x >> 6;
  const int gw = blockIdx.x * 4 + wave;
  const int nw = gridDim.x * 4;
  float wv[16], acc[16];
#pragma unroll
  for (int q = 0; q < 4; ++q) {
    const float4 tv = *reinterpret_cast<const float4*>(win + q * 256 + lane * 4);
    wv[q*4+0] = tv.x; wv[q*4+1] = tv.y; wv[q*4+2] = tv.z; wv[q*4+3] = tv.w;
  }
#pragma unroll
  for (int j = 0; j < 16; ++j) acc[j] = 0.f;
  for (int i = gw; i < P_ROWS; i += nw) {
    const float* xr = X + (size_t)i * D_DIM;
    float xv[16];
    float dot = 0.f;
#pragma unroll
    for (int q = 0; q < 4; ++q) {
      const float4 tv = *reinterpret_cast<const float4*>(xr + q * 256 + lane * 4);
      xv[q*4+0] = tv.x; xv[q*4+1] = tv.y; xv[q*4+2] = tv.z; xv[q*4+3] = tv.w;
      dot += tv.x * wv[q*4+0] + tv.y * wv[q*4+1] + tv.z * wv[q*4+2] + tv.w * wv[q*4+3];
    }
#pragma unroll
    for (int m = 1; m < 64; m <<= 1) dot += __shfl_xor(dot, m);
#pragma unroll
    for (int j = 0; j < 16; ++j) acc[j] += dot * xv[j];
  }
#pragma unroll
  for (int q = 0; q < 4; ++q) {
    float4 tv;
    tv.x = acc[q*4+0]; tv.y = acc[q*4+1]; tv.z = acc[q*4+2]; tv.w = acc[q*4+3];
    *reinterpret_cast<float4*>(&red[wave][q * 256 + lane * 4]) = tv;
  }
  __syncthreads();
  const int d0 = threadIdx.x * 4;
#pragma unroll
  for (int j = 0; j < 4; ++j)
    atomicAdd(wout + d0 + j, red[0][d0+j] + red[1][d0+j] + red[2][d0+j] + red[3][d0+j]);
}

// rep = gamma*(64 v - 2016 eps u1/P + 41664 eps^2 u2/P^2); emit rep/(L*P) and rep/||rep||
__global__ void combine_kernel(const float* __restrict__ v, const float* __restrict__ u1,
                               const float* __restrict__ u2, const float* __restrict__ gamma_p,
                               float* __restrict__ rep_lin, float* __restrict__ repn) {
  __shared__ float sred[4];
  const float gamma = *gamma_p;
  const float eps = gamma / (float)L_STEPS;
  const float c1 = 2016.0f * eps / (float)P_ROWS;
  const float c2 = 41664.0f * eps * eps / ((float)P_ROWS * (float)P_ROWS);
  const int d0 = threadIdx.x * 4;
  float r[4];
  float ss = 0.f;
#pragma unroll
  for (int j = 0; j < 4; ++j) {
    const float val = gamma * ((float)L_STEPS * v[d0+j] - c1 * u1[d0+j] + c2 * u2[d0+j]);
    r[j] = val;
    ss += val * val;
  }
#pragma unroll
  for (int m = 1; m < 64; m <<= 1) ss += __shfl_xor(ss, m);
  if ((threadIdx.x & 63) == 0) sred[threadIdx.x >> 6] = ss;
  __syncthreads();
  const float norm = sqrtf(sred[0] + sred[1] + sred[2] + sred[3]);
  const float inv_norm = 1.0f / (norm + 1e-8f);
  const float lin_s = 1.0f / ((float)L_STEPS * (float)P_ROWS);
#pragma unroll
  for (int j = 0; j < 4; ++j) {
    rep_lin[d0+j] = r[j] * lin_s;
    repn[d0+j]    = r[j] * inv_norm;
  }
}

// WnF fragment-major: byte addr (s*32+f)*1024 + l*16 holds bf16 x8 of
// W[f*16+(l&15)][s*32+(l>>4)*8 + 0..7] * repn[...]
__global__ void wn_frag_kernel(const float* __restrict__ W, const float* __restrict__ repn,
                               ushort* __restrict__ WnF) {
  const int gid = blockIdx.x * 256 + threadIdx.x;   // 65536
  const int l = gid & 63;
  const int f = (gid >> 6) & 31;
  const int s = gid >> 11;
  const int m = f * 16 + (l & 15);
  const int d0 = s * 32 + ((l >> 4) << 3);
  const float4 w0 = *reinterpret_cast<const float4*>(W + (size_t)m * D_DIM + d0);
  const float4 w1 = *reinterpret_cast<const float4*>(W + (size_t)m * D_DIM + d0 + 4);
  const float4 r0 = *reinterpret_cast<const float4*>(repn + d0);
  const float4 r1 = *reinterpret_cast<const float4*>(repn + d0 + 4);
  uint4 o;
  o.x = f2bf(w0.x*r0.x) | (f2bf(w0.y*r0.y) << 16);
  o.y = f2bf(w0.z*r0.z) | (f2bf(w0.w*r0.w) << 16);
  o.z = f2bf(w1.x*r1.x) | (f2bf(w1.y*r1.y) << 16);
  o.w = f2bf(w1.z*r1.z) | (f2bf(w1.w*r1.w) << 16);
  *reinterpret_cast<uint4*>(WnF + (size_t)gid * 8) = o;
}

// Fused GEMM, round 12: barrier-free register streaming, compiler-scheduled.
// BM=128, 512 threads = 8 waves (2 wm x 4 wn), wave tile 64x128, BK=32, 32 steps.
// NO LDS for A/B, NO s_barrier / sched_barrier / setprio / manual vmcnt in the
// loop: A f32 direct from Xs (L1 serves the 4-way wm duplication), B from the
// L2-resident fragment-major WnF. The compiler inserts exact per-use waitcnts,
// interleaves loads with MFMAs, and waves drift freely (real TLP).
// Register budget (unified RF, 256/wave at 2 waves/SIMD): acc 128 AGPR +
// ~100 VGPR -> fits under __launch_bounds__(512,2) without spill.
__global__ __launch_bounds__(512, 2)
void fused_kernel(const float* __restrict__ Xs, const ushort* __restrict__ WnF,
                  const float* __restrict__ rep_lin, const float* __restrict__ b1,
                  const float* __restrict__ aw, const float* __restrict__ b2p,
                  float* __restrict__ out) {
  __shared__ float mlp_acc[BM];
  __shared__ float lin_acc[BM];

  const int t = threadIdx.x;
  const int lane = t & 63;
  const int wid = t >> 6;
  const int wm = wid >> 2;     // 0..1
  const int wn = wid & 3;      // 0..3
  const int fr = lane & 15;
  const int kg = lane >> 4;
  const size_t blockRow = (size_t)blockIdx.x * BM;

  // A: row = blockRow + wm*64 + fr + mi*16, bytes col = s*128 + kg*32 (+16 for vb)
  const char* gA = (const char*)Xs + (blockRow + (size_t)(wm * 64 + fr)) * XS_ROW_BYTES
                 + (size_t)kg * 32;
  // B: fragment-major; wave wn owns n-frags wn*8 + ni
  const char* gB = (const char*)WnF + (size_t)(wn * 8) * 1024 + (size_t)lane * 16;
  // rep_lin for the linear term (wn==0 waves only)
  const char* gR = (const char*)rep_lin + (size_t)kg * 32;

  if (t < BM) mlp_acc[t] = 0.f;

  f32x4_t acc[4][8];
#pragma unroll
  for (int mi = 0; mi < 4; ++mi)
#pragma unroll
    for (int ni = 0; ni < 8; ++ni)
      acc[mi][ni] = f32x4_t{0.f, 0.f, 0.f, 0.f};
  float lin[4] = {0.f, 0.f, 0.f, 0.f};

  for (int s = 0; s < 32; ++s) {
    const char* gBs = gB + (size_t)s * 32768;
    const char* gAs = gA + (size_t)s * 128;
    uint4 Bv[8];
#pragma unroll
    for (int ni = 0; ni < 8; ++ni)
      Bv[ni] = *reinterpret_cast<const uint4*>(gBs + ni * 1024);
    f32x4_t va[4], vb[4];
#pragma unroll
    for (int mi = 0; mi < 4; ++mi) {
      va[mi] = *reinterpret_cast<const f32x4_t*>(gAs + mi * 65536);
      vb[mi] = *reinterpret_cast<const f32x4_t*>(gAs + mi * 65536 + 16);
    }
    if (wn == 0) {
      const f32x4_t rp0 = *reinterpret_cast<const f32x4_t*>(gR + s * 128);
      const f32x4_t rp1 = *reinterpret_cast<const f32x4_t*>(gR + s * 128 + 16);
#pragma unroll
      for (int mi = 0; mi < 4; ++mi)
        lin[mi] += va[mi][0]*rp0[0] + va[mi][1]*rp0[1] + va[mi][2]*rp0[2] + va[mi][3]*rp0[3]
                 + vb[mi][0]*rp1[0] + vb[mi][1]*rp1[1] + vb[mi][2]*rp1[2] + vb[mi][3]*rp1[3];
    }
    bf16x8_t afr[4];
#pragma unroll
    for (int mi = 0; mi < 4; ++mi)
      afr[mi] = cvt_frag(va[mi], vb[mi]);
#pragma unroll
    for (int mi = 0; mi < 4; ++mi)
#pragma unroll
      for (int ni = 0; ni < 8; ++ni)
        acc[mi][ni] = __builtin_amdgcn_mfma_f32_16x16x32_bf16(afr[mi], as_bf16x8(Bv[ni]), acc[mi][ni], 0, 0, 0);
  }

  // ---- epilogue ----
  float b1r[8], ar[8];
#pragma unroll
  for (int ni = 0; ni < 8; ++ni) {
    const int c = wn * 128 + ni * 16 + fr;
    b1r[ni] = b1[c];
    ar[ni]  = aw[c];
  }
#pragma unroll
  for (int mi = 0; mi < 4; ++mi) {
#pragma unroll
    for (int r = 0; r < 4; ++r) {
      float sum = 0.f;
#pragma unroll
      for (int ni = 0; ni < 8; ++ni) {
        const float h = acc[mi][ni][r] + b1r[ni];
        sum += fmaxf(h, 0.f) * ar[ni];
      }
      sum += __shfl_xor(sum, 1);
      sum += __shfl_xor(sum, 2);
      sum += __shfl_xor(sum, 4);
      sum += __shfl_xor(sum, 8);
      if (fr == 0) {
        const int row = wm * 64 + mi * 16 + kg * 4 + r;
        atomicAdd(&mlp_acc[row], sum);
      }
    }
  }
  if (wn == 0) {
#pragma unroll
    for (int mi = 0; mi < 4; ++mi) {
      lin[mi] += __shfl_xor(lin[mi], 16);
      lin[mi] += __shfl_xor(lin[mi], 32);
    }
    if (lane < 16) {
#pragma unroll
      for (int mi = 0; mi < 4; ++mi)
        lin_acc[wm * 64 + mi * 16 + lane] = lin[mi];
    }
  }
  __syncthreads();
  if (t < BM)
    out[blockRow + t] = lin_acc[t] + mlp_acc[t] + b2p[0];
}

extern "C" void kernel_launch(void* const* d_in, const int* in_sizes, int n_in,
                              void* d_out, int out_size, void* d_ws, size_t ws_size,
                              hipStream_t stream) {
  const float* X     = (const float*)d_in[0];
  const float* y     = (const float*)d_in[1];
  const float* Xs    = (const float*)d_in[2];
  const float* gamma = (const float*)d_in[3];
  const float* W     = (const float*)d_in[4];
  const float* a     = (const float*)d_in[5];
  const float* b1    = (const float*)d_in[6];
  const float* b2    = (const float*)d_in[7];
  float* out = (float*)d_out;

  char* ws = (char*)d_ws;
  float*  v       = (float*)(ws + 0);
  float*  u1      = (float*)(ws + 4096);
  float*  u2      = (float*)(ws + 8192);
  float*  rep_lin = (float*)(ws + 12288);
  float*  repn    = (float*)(ws + 16384);
  ushort* WnF     = (ushort*)(ws + 20480);

  hipMemsetAsync(ws, 0, 3 * 4096, stream);
  hipLaunchKernelGGL(xty_kernel,     dim3(256), dim3(256), 0, stream, X, y, v);
  hipLaunchKernelGGL(xtxw_kernel,    dim3(256), dim3(256), 0, stream, X, v, u1);
  hipLaunchKernelGGL(xtxw_kernel,    dim3(256), dim3(256), 0, stream, X, u1, u2);
  hipLaunchKernelGGL(combine_kernel, dim3(1),   dim3(256), 0, stream, v, u1, u2, gamma, rep_lin, repn);
  hipLaunchKernelGGL(wn_frag_kernel, dim3(256), dim3(256), 0, stream, W, repn, WnF);
  hipLaunchKernelGGL(fused_kernel,   dim3(K_ROWS / BM), dim3(512), 0, stream,
                     Xs, WnF, rep_lin, b1, a, b2, out);
}